// Round 10
// baseline (199.093 us; speedup 1.0000x reference)
//
#include <hip/hip_runtime.h>

// ---------------------------------------------------------------------------
// MoE cross-attention decoder layer on MI355X (gfx950), bf16 MFMA pipeline.
// R19: (1) revert R18 head-major K/V (it cost qkv ~3us in scattered stores,
// gained attn nothing -> attn is not request-bound). (2) gemm_qkv: one
// 512-thread block per (row-block, role-expert) covering the FULL N=256 -
// A-tile staged to LDS once instead of twice (86->43 MB staged), 8 waves
// each own a 64x64 output tile, per-thread code identical to R14 (acc[4][4],
// vmcnt(2) counted wait). XCD alignment: id = rb + 128*zr == rb mod 8.
// (3) attn split 4->1: each block loops 4x256 keys; PO halves to 4.1MB,
// Q read once, gemm_og single-split. cvt_all / finalize unchanged.
// ---------------------------------------------------------------------------

typedef __bf16 bf16x8 __attribute__((ext_vector_type(8)));
typedef float f32x4 __attribute__((ext_vector_type(4)));
typedef unsigned int u32x4 __attribute__((ext_vector_type(4)));
typedef unsigned int u32x2 __attribute__((ext_vector_type(2)));
typedef unsigned short u16x4 __attribute__((ext_vector_type(4)));
typedef unsigned short us;

__device__ __forceinline__ us f2bf(float f) {
    unsigned u = __builtin_bit_cast(unsigned, f);
    u += 0x7FFFu + ((u >> 16) & 1u);
    return (us)(u >> 16);
}

__device__ __forceinline__ unsigned pack2(float lo, float hi) {
    return (unsigned)f2bf(lo) | ((unsigned)f2bf(hi) << 16);
}

__device__ __forceinline__ float bf2f(us v) {
    unsigned u = ((unsigned)v) << 16;
    return __builtin_bit_cast(float, u);
}

__device__ __forceinline__ bf16x8 ld_bf8(const us* p) {
    return __builtin_bit_cast(bf16x8, *reinterpret_cast<const u32x4*>(p));
}

__device__ __forceinline__ void gld_lds16(const us* g, us* l) {
    __builtin_amdgcn_global_load_lds(
        (const __attribute__((address_space(1))) unsigned int*)g,
        (__attribute__((address_space(3))) unsigned int*)l, 16, 0, 0);
}

// ---------------- fused converts + gate softmax ----------------------------
// Wb is written FRAGMENT-MAJOR: per (e,role) 65536-elem block laid out as
// [g 0..31][col 0..255][8], g = k/8.
__launch_bounds__(256)
__global__ void cvt_all(const float* __restrict__ tgt, const float* __restrict__ qpos,
                        const float* __restrict__ mem, const float* __restrict__ pos,
                        const float* __restrict__ w_in, const float* __restrict__ w_out,
                        const float* __restrict__ w_gate, const float* __restrict__ b_gate,
                        us* __restrict__ Aq, us* __restrict__ Ak, us* __restrict__ Av,
                        us* __restrict__ Wb, us* __restrict__ WOb,
                        float* __restrict__ Gate)
{
    const int bid = blockIdx.x;
    const int tid = threadIdx.x;
    if (bid < 400) {
        const int i = bid * 256 + tid;
        const int lane = tid & 63;
        const int row = i >> 6;                 // = 4*bid + wave
        f32x4 a = reinterpret_cast<const f32x4*>(tgt)[i];
        f32x4 b = reinterpret_cast<const f32x4*>(qpos)[i];
        u16x4 r;
#pragma unroll
        for (int j = 0; j < 4; ++j) r[j] = f2bf(a[j] + b[j]);
        reinterpret_cast<u16x4*>(Aq)[i] = r;
        float g[5];
#pragma unroll
        for (int e = 0; e < 5; ++e) {
            f32x4 wg = *reinterpret_cast<const f32x4*>(w_gate + e * 256 + 4 * lane);
            float p = a[0] * wg[0] + a[1] * wg[1] + a[2] * wg[2] + a[3] * wg[3];
#pragma unroll
            for (int off = 32; off >= 1; off >>= 1) p += __shfl_xor(p, off, 64);
            g[e] = p + b_gate[e];
        }
        float mx = g[0];
#pragma unroll
        for (int e = 1; e < 5; ++e) mx = fmaxf(mx, g[e]);
        float sm = 0.0f;
#pragma unroll
        for (int e = 0; e < 5; ++e) { g[e] = __expf(g[e] - mx); sm += g[e]; }
        const float invs = 1.0f / sm;
        if (lane == 0) {
#pragma unroll
            for (int e = 0; e < 5; ++e) Gate[row * 5 + e] = g[e] * invs;
        }
    } else if (bid < 4496) {
        int i = (bid - 400) * 256 + tid;
        f32x4 m = reinterpret_cast<const f32x4*>(mem)[i];
        f32x4 p = reinterpret_cast<const f32x4*>(pos)[i];
        u16x4 rk, rv;
#pragma unroll
        for (int j = 0; j < 4; ++j) { rk[j] = f2bf(m[j] + p[j]); rv[j] = f2bf(m[j]); }
        reinterpret_cast<u16x4*>(Ak)[i] = rk;
        reinterpret_cast<u16x4*>(Av)[i] = rv;
    } else if (bid < 5456) {
        int i = (bid - 4496) * 256 + tid;       // f32x4 index into w_in
        f32x4 a = reinterpret_cast<const f32x4*>(w_in)[i];
        u16x4 r;
#pragma unroll
        for (int j = 0; j < 4; ++j) r[j] = f2bf(a[j]);
        const int e    = i / 49152;             // 768*64
        const int rem  = i % 49152;
        const int row  = rem >> 6;              // 0..767
        const int kq4  = rem & 63;
        const int role = row >> 8;              // 0=q 1=k 2=v
        const int col  = row & 255;
        const int g    = kq4 >> 1;              // k granule (8 elems)
        const int sub  = kq4 & 1;
        const size_t dst = (size_t)(e * 3 + role) * 65536
                         + ((size_t)(g * 256 + col)) * 8 + sub * 4;
        *reinterpret_cast<u16x4*>(Wb + dst) = r;
    } else {
        int i = (bid - 5456) * 256 + tid;
        f32x4 a = reinterpret_cast<const f32x4*>(w_out)[i];
        u16x4 r;
#pragma unroll
        for (int j = 0; j < 4; ++j) r[j] = f2bf(a[j]);
        reinterpret_cast<u16x4*>(WOb)[i] = r;
    }
}

// ---------------- QKV projection (R19: 512-thread full-N blocks) -----------
// grid (128, 15): x = row block, y = role-expert. A-tile staged ONCE per
// block (8 waves share it); wave w owns output tile (wm,wn) =
// ((w>>2)*64, (w&3)*64) of the 128x256 result. W direct from fragment-major
// Wb. Per-wave queue: [stage_kt(2), W_kt(8), stage_kt+1(2)] -> vmcnt(2).
__launch_bounds__(512, 4)
__global__ void gemm_qkv(const us* __restrict__ Aq, const us* __restrict__ Ak,
                         const us* __restrict__ Av, const us* __restrict__ Wb,
                         const float* __restrict__ b_in,
                         us* __restrict__ Qb, us* __restrict__ Kb, us* __restrict__ Vb)
{
    const int rb = blockIdx.x;         // row block
    const int zr = blockIdx.y;         // role-expert
    const us* A; const us* W; const float* bias; us* C;
    float scale; int M;
    if (zr < 5) {
        if (rb >= 13) return;
        A = Aq; W = Wb + (size_t)zr * 196608; bias = b_in + (size_t)zr * 768;
        C = Qb + (size_t)zr * 409600; scale = 0.17677669529663687f; M = 1600;
    } else if (zr < 10) {
        const int e = zr - 5;
        A = Ak; W = Wb + 65536 + (size_t)e * 196608; bias = b_in + (size_t)e * 768 + 256;
        C = Kb + (size_t)e * 4194304; scale = 1.0f; M = 16384;
    } else {
        const int e = zr - 10;
        A = Av; W = Wb + 131072 + (size_t)e * 196608; bias = b_in + (size_t)e * 768 + 512;
        C = Vb + (size_t)e * 4194304; scale = 1.0f; M = 16384;
    }
    const int row0 = rb * 128;

    __shared__ us As[2 * 8192];        // 32 KB: A-tile double buffer only
    const int tid  = threadIdx.x;
    const int lane = tid & 63;
    const int w    = tid >> 6;         // 0..7
    const int l15  = lane & 15;
    const int quad = lane >> 4;
    const int wm   = (w >> 2) * 64;    // row half
    const int wn   = (w & 3) * 64;     // col quarter
    const int srow = lane >> 3;
    const int gofs = ((lane & 7) ^ srow) * 8;

    // per-wave A stage: 2 gld_lds16 (8 waves x 2 = 16KB k-slice)
    auto stageA = [&](int buf, int kt) {
#pragma unroll
        for (int cc = 0; cc < 2; ++cc) {
            const int c = w * 2 + cc;
            gld_lds16(A + (size_t)(row0 + c * 8 + srow) * 256 + kt * 64 + gofs,
                      &As[buf * 8192 + c * 512]);
        }
    };

    f32x4 acc[4][4] = {};

    stageA(0, 0);
    __builtin_amdgcn_sched_barrier(0);

#pragma unroll
    for (int kt = 0; kt < 4; ++kt) {
        const int cur = kt & 1;
        u32x4 bf[2][4];
#pragma unroll
        for (int kh = 0; kh < 2; ++kh)
#pragma unroll
            for (int ni = 0; ni < 4; ++ni)
                bf[kh][ni] = *reinterpret_cast<const u32x4*>(
                    W + (((size_t)(kt * 8 + kh * 4 + quad) * 256
                          + (wn + ni * 16 + l15)) * 8));
        __builtin_amdgcn_sched_barrier(0);
        if (kt < 3) stageA(cur ^ 1, kt + 1);
        __builtin_amdgcn_sched_barrier(0);
        // retire stage(kt) [oldest] + W(kt); leave stage(kt+1)'s 2 in flight
        if (kt < 3) asm volatile("s_waitcnt vmcnt(2)" ::: "memory");
        else        asm volatile("s_waitcnt vmcnt(0)" ::: "memory");
        __builtin_amdgcn_s_barrier();          // all waves' stage(kt) landed
        __builtin_amdgcn_sched_barrier(0);
#pragma unroll
        for (int kh = 0; kh < 2; ++kh) {
            bf16x8 af[4];
#pragma unroll
            for (int mi = 0; mi < 4; ++mi) {
                const int row = wm + mi * 16 + l15;
                const int seg = (kh * 4 + quad) ^ (row & 7);
                af[mi] = ld_bf8(&As[cur * 8192 + row * 64 + seg * 8]);
            }
#pragma unroll
            for (int mi = 0; mi < 4; ++mi)
#pragma unroll
                for (int ni = 0; ni < 4; ++ni)
                    acc[mi][ni] = __builtin_amdgcn_mfma_f32_16x16x32_bf16(
                        __builtin_bit_cast(bf16x8, bf[kh][ni]), af[mi], acc[mi][ni], 0, 0, 0);
        }
        if (kt < 3) {
            asm volatile("s_waitcnt lgkmcnt(0)" ::: "memory");
            __builtin_amdgcn_sched_barrier(0);
            __builtin_amdgcn_s_barrier();      // all waves done reading As[cur]
            __builtin_amdgcn_sched_barrier(0);
        }
    }

    // ---- epilogue: bias + scale + pack bf16 + store (row-major) ----
#pragma unroll
    for (int mi = 0; mi < 4; ++mi) {
        const int row = row0 + wm + mi * 16 + l15;
        if (row < M) {
#pragma unroll
            for (int ni = 0; ni < 4; ++ni) {
                const int colb = wn + ni * 16 + quad * 4;
                const f32x4 b4 = *reinterpret_cast<const f32x4*>(bias + colb);
                u32x2 pk;
                pk[0] = pack2((acc[mi][ni][0] + b4[0]) * scale,
                              (acc[mi][ni][1] + b4[1]) * scale);
                pk[1] = pack2((acc[mi][ni][2] + b4[2]) * scale,
                              (acc[mi][ni][3] + b4[3]) * scale);
                *reinterpret_cast<u32x2*>(C + (size_t)row * 256 + colb) = pk;
            }
        }
    }
}

// ---------------- out-proj GEMM (single split) -----------------------------
// grid (16, 2, 5): x = row block (>=13 idle; pads y-sibling stride to 16 = 0
// mod 8 so both col-blocks' identical PO-row reads hit the same XCD L2).
__launch_bounds__(256)
__global__ void gemm_og(const us* __restrict__ PO, const float* __restrict__ PL,
                        const us* __restrict__ WOb, const float* __restrict__ b_out,
                        float* __restrict__ OUTf)
{
    if (blockIdx.x >= 13) return;
    const int e = blockIdx.z;
    const us* W = WOb + (size_t)e * 65536;
    const float* bias = b_out + (size_t)e * 256;
    float* Cout = OUTf + (size_t)e * 409600;

    const int row0 = blockIdx.x * 128;
    const int col0 = blockIdx.y * 128;
    __shared__ us As[2 * 8192];
    __shared__ us Bs[2 * 8192];
    const int tid  = threadIdx.x;
    const int lane = tid & 63;
    const int w    = tid >> 6;
    const int l15  = lane & 15;
    const int quad = lane >> 4;
    const int wm   = (w >> 1) * 64;
    const int wn   = (w & 1) * 64;
    const int srow = lane >> 3;
    const int gofs = ((lane & 7) ^ srow) * 8;

    u32x4 POr[4];
    float Lr[4];

    auto loadA = [&](int kt) {
#pragma unroll
        for (int cc = 0; cc < 4; ++cc) {
            const int c = w * 4 + cc;
            int grow = row0 + c * 8 + srow;
            if (grow > 1599) grow = 1599;
            const int d0 = kt * 64 + gofs;
            POr[cc] = *reinterpret_cast<const u32x4*>(
                PO + (size_t)e * 409600 + (size_t)grow * 256 + d0);
            const int l = grow >> 4, bb = grow & 15, hh = d0 >> 5;
            Lr[cc] = PL[(((size_t)e * 16 + bb) * 8 + hh) * 128 + l];
        }
    };
    auto writeA = [&](int buf) {
#pragma unroll
        for (int cc = 0; cc < 4; ++cc) {
            const float inv = 1.0f / Lr[cc];
            u32x4 pk;
#pragma unroll
            for (int j = 0; j < 4; ++j) {
                const unsigned u = POr[cc][j];
                const float v0 = __builtin_bit_cast(float, u << 16);
                const float v1 = __builtin_bit_cast(float, u & 0xffff0000u);
                pk[j] = pack2(v0 * inv, v1 * inv);
            }
            *reinterpret_cast<u32x4*>(&As[buf * 8192 + (w * 4 + cc) * 512 + lane * 8]) = pk;
        }
    };
    auto loadW = [&](int buf, int kt) {
#pragma unroll
        for (int cc = 0; cc < 4; ++cc) {
            const int c = w * 4 + cc;
            const int row = c * 8 + srow;
            gld_lds16(W + (size_t)(col0 + row) * 256 + kt * 64 + gofs,
                      &Bs[buf * 8192 + c * 512]);
        }
    };

    loadA(0);
    loadW(0, 0);
    writeA(0);
    __syncthreads();

    f32x4 acc[4][4] = {};

#pragma unroll
    for (int kt = 0; kt < 4; ++kt) {
        const int cur = kt & 1;
        if (kt < 3) {
            loadA(kt + 1);
            loadW(cur ^ 1, kt + 1);
        }
#pragma unroll
        for (int kh = 0; kh < 2; ++kh) {
            bf16x8 af[4], bf[4];
#pragma unroll
            for (int mi = 0; mi < 4; ++mi) {
                const int row = wm + mi * 16 + l15;
                const int seg = (kh * 4 + quad) ^ (row & 7);
                af[mi] = ld_bf8(&As[cur * 8192 + row * 64 + seg * 8]);
            }
#pragma unroll
            for (int ni = 0; ni < 4; ++ni) {
                const int col = wn + ni * 16 + l15;
                const int seg = (kh * 4 + quad) ^ (col & 7);
                bf[ni] = ld_bf8(&Bs[cur * 8192 + col * 64 + seg * 8]);
            }
#pragma unroll
            for (int mi = 0; mi < 4; ++mi)
#pragma unroll
                for (int ni = 0; ni < 4; ++ni)
                    acc[mi][ni] = __builtin_amdgcn_mfma_f32_16x16x32_bf16(bf[ni], af[mi], acc[mi][ni], 0, 0, 0);
        }
        if (kt < 3) {
            writeA(cur ^ 1);
            __syncthreads();
        }
    }

#pragma unroll
    for (int mi = 0; mi < 4; ++mi) {
        const int row = row0 + wm + mi * 16 + l15;
        if (row < 1600) {
#pragma unroll
            for (int ni = 0; ni < 4; ++ni) {
                const int colb = col0 + wn + ni * 16 + quad * 4;
                const f32x4 b4 = *reinterpret_cast<const f32x4*>(bias + colb);
                f32x4 v;
#pragma unroll
                for (int r = 0; r < 4; ++r) v[r] = acc[mi][ni][r] + b4[r];
                *reinterpret_cast<f32x4*>(Cout + (size_t)row * 256 + colb) = v;
            }
        }
    }
}

// ---------------- attention (R19: split-1, 4 chunks per block) -------------
// grid (80, 8): x = e*16+b, y = head (head-siblings differ by 80 = 0 mod 8
// -> same XCD). Row-major Kb/Vb (R17 layout). QK/PV pipeline from R17.
__device__ __forceinline__ int vrow(int d) { return d * 264 + 8 * (d >> 3); }

__launch_bounds__(512)
__global__ void attn(const us* __restrict__ Qb, const us* __restrict__ Kb,
                     const us* __restrict__ Vb, us* __restrict__ PO,
                     float* __restrict__ PL)
{
    const int z = blockIdx.x;
    const int h = blockIdx.y;
    const int e = z >> 4, b = z & 15;
    const int tid  = threadIdx.x;
    const int w    = tid >> 6;
    const int lane = tid & 63;
    const int l15  = lane & 15, quad = lane >> 4;
    __shared__ us Ks[256 * 32];
    __shared__ us Vs[8464];
    __shared__ us Ps[7][2][16 * 40];   // double-buffered per wave

    // Q fragment loaded once
    u32x4 qraw = {0u, 0u, 0u, 0u};
    if (w < 7) {
        const int l = w * 16 + l15;
        if (l < 100)
            qraw = *reinterpret_cast<const u32x4*>(
                Qb + ((size_t)((e * 100 + l) * 16 + b)) * 256 + h * 32 + quad * 8);
    }
    const bf16x8 qf = __builtin_bit_cast(bf16x8, qraw);

    const f32x4 zacc = {};
    f32x4 o0 = {}, o1 = {};
    float lsum = 0.0f;

    for (int sc = 0; sc < 4; ++sc) {
        const int key0 = sc * 256;
        if (sc) __syncthreads();    // prior chunk's LDS reads complete
        {
            const int kl  = lane >> 2;
            const int seg = lane & 3;
            const us* kg = Kb + ((size_t)((e * 1024 + key0 + w * 16 + kl) * 16 + b)) * 256
                              + h * 32 + seg * 8;
            gld_lds16(kg, &Ks[w * 512]);
            gld_lds16(kg + (size_t)128 * 16 * 256, &Ks[4096 + w * 512]);

            const int kv = tid >> 2;
            const int sg = tid & 3;
            const us* vg = Vb + ((size_t)((e * 1024 + key0 + kv) * 16 + b)) * 256
                              + h * 32 + sg * 8;
            u32x4 v0 = *reinterpret_cast<const u32x4*>(vg);
            u32x4 v1 = *reinterpret_cast<const u32x4*>(vg + (size_t)128 * 16 * 256);
#pragma unroll
            for (int j = 0; j < 4; ++j) {
                const int d0 = sg * 8 + 2 * j;
                const int e0 = vrow(d0);
                const int e1 = e0 + 264;
                Vs[e0 + kv]       = (us)(v0[j] & 0xffff);
                Vs[e1 + kv]       = (us)(v0[j] >> 16);
                Vs[e0 + 128 + kv] = (us)(v1[j] & 0xffff);
                Vs[e1 + 128 + kv] = (us)(v1[j] >> 16);
            }
        }
        __syncthreads();

        if (w < 7) {
            auto qk = [&](int c) {
                bf16x8 kf0 = ld_bf8(&Ks[(c * 32 + l15) * 32 + quad * 8]);
                bf16x8 kf1 = ld_bf8(&Ks[(c * 32 + 16 + l15) * 32 + quad * 8]);
                f32x4 s0 = __builtin_amdgcn_mfma_f32_16x16x32_bf16(kf0, qf, zacc, 0, 0, 0);
                f32x4 s1 = __builtin_amdgcn_mfma_f32_16x16x32_bf16(kf1, qf, zacc, 0, 0, 0);
                float p0[4], p1[4];
#pragma unroll
                for (int r = 0; r < 4; ++r) {
                    p0[r] = __expf(s0[r]);
                    p1[r] = __expf(s1[r]);
                    lsum += p0[r] + p1[r];
                }
                u32x2 w0, w1;
                w0[0] = pack2(p0[0], p0[1]);
                w0[1] = pack2(p0[2], p0[3]);
                w1[0] = pack2(p1[0], p1[1]);
                w1[1] = pack2(p1[2], p1[3]);
                us* psb = &Ps[w][c & 1][0];
                *reinterpret_cast<u32x2*>(&psb[l15 * 40 + quad * 4])      = w0;
                *reinterpret_cast<u32x2*>(&psb[l15 * 40 + 16 + quad * 4]) = w1;
            };
            auto pv = [&](int c) {
                bf16x8 pf  = ld_bf8(&Ps[w][c & 1][l15 * 40 + quad * 8]);
                bf16x8 vf0 = ld_bf8(&Vs[vrow(l15) + c * 32 + quad * 8]);
                bf16x8 vf1 = ld_bf8(&Vs[vrow(16 + l15) + c * 32 + quad * 8]);
                o0 = __builtin_amdgcn_mfma_f32_16x16x32_bf16(pf, vf0, o0, 0, 0, 0);
                o1 = __builtin_amdgcn_mfma_f32_16x16x32_bf16(pf, vf1, o1, 0, 0, 0);
            };
            qk(0);
#pragma unroll
            for (int c = 1; c < 8; ++c) {
                qk(c);      // exp VALU of chunk c ...
                pv(c - 1);  // ... overlaps PV MFMA of chunk c-1
            }
            pv(7);
        }
    }

    if (w >= 7) return;

    lsum += __shfl_xor(lsum, 16, 64);
    lsum += __shfl_xor(lsum, 32, 64);

#pragma unroll
    for (int r = 0; r < 4; ++r) {
        const int row = w * 16 + quad * 4 + r;
        if (row < 100) {
            const size_t o = (((size_t)(e * 100 + row)) * 16 + b) * 256 + h * 32;
            PO[o + l15]      = f2bf(o0[r]);
            PO[o + 16 + l15] = f2bf(o1[r]);
        }
    }
    const int q = w * 16 + l15;
    if (quad == 0 && q < 100)
        PL[(((size_t)e * 16 + b) * 8 + h) * 128 + q] = lsum;
}

// ---------------- gate-weighted mix + residual + LayerNorm -----------------
__launch_bounds__(256)
__global__ void finalize(const float* __restrict__ tgt, const float* __restrict__ Gate,
                         const float* __restrict__ OUTf,
                         const float* __restrict__ gamma, const float* __restrict__ beta,
                         float* __restrict__ out)
{
    const int row = blockIdx.x;
    const int d = threadIdx.x;
    __shared__ float red[8];
    const float t = tgt[(size_t)row * 256 + d];

    float mo = 0.0f;
#pragma unroll
    for (int e = 0; e < 5; ++e)
        mo += Gate[row * 5 + e] * OUTf[((size_t)e * 1600 + row) * 256 + d];
    const float x = t + mo;

    float p1 = x, p2 = x * x;
#pragma unroll
    for (int off = 32; off >= 1; off >>= 1) {
        p1 += __shfl_xor(p1, off, 64);
        p2 += __shfl_xor(p2, off, 64);
    }
    if ((d & 63) == 0) { red[d >> 6] = p1; red[4 + (d >> 6)] = p2; }
    __syncthreads();
    const float mean = (red[0] + red[1] + red[2] + red[3]) * (1.0f / 256.0f);
    const float msq  = (red[4] + red[5] + red[6] + red[7]) * (1.0f / 256.0f);
    const float var  = msq - mean * mean;

    out[(size_t)row * 256 + d] = (x - mean) * rsqrtf(var + 1e-5f) * gamma[d] + beta[d];
}

// ---------------------------------------------------------------------------
extern "C" void kernel_launch(void* const* d_in, const int* in_sizes, int n_in,
                              void* d_out, int out_size, void* d_ws, size_t ws_size,
                              hipStream_t stream)
{
    const float* tgt    = (const float*)d_in[0];
    const float* mem    = (const float*)d_in[1];
    const float* qpos   = (const float*)d_in[2];
    const float* pos    = (const float*)d_in[3];
    const float* w_in   = (const float*)d_in[4];
    const float* b_in   = (const float*)d_in[5];
    const float* w_out  = (const float*)d_in[6];
    const float* b_out  = (const float*)d_in[7];
    const float* w_gate = (const float*)d_in[8];
    const float* b_gate = (const float*)d_in[9];
    const float* ln_g   = (const float*)d_in[10];
    const float* ln_b   = (const float*)d_in[11];
    float* out = (float*)d_out;

    char* p = (char*)d_ws;
    auto alloc = [&](size_t n) { char* r = p; p += (n + 255) & ~(size_t)255; return r; };

    us* Aq   = (us*)alloc(409600ull * 2);       // dead after gemm_qkv
    us* Ak   = (us*)alloc(4194304ull * 2);      // dead after gemm_qkv
    us* Av   = (us*)alloc(4194304ull * 2);      // dead after gemm_qkv
    us* Wb   = (us*)alloc(983040ull * 2);
    us* WOb  = (us*)alloc(327680ull * 2);
    us* Qb   = (us*)alloc(5ull * 409600 * 2);
    us* Kb   = (us*)alloc(5ull * 4194304 * 2);
    us* Vb   = (us*)alloc(5ull * 4194304 * 2);
    float* OUTf  = (float*)alloc(5ull * 409600 * 4);
    float* Gate  = (float*)alloc(1600ull * 5 * 4);
    // Attention partials alias the dead cvt region (Aq..Av): 4.1+0.33 < 17.7 MB
    us*    PO = (us*)d_ws;                          // [5][100][16][256] bf16
    float* PL = (float*)((char*)d_ws + 4096000);    // [5*16*8][128] f32

    cvt_all<<<5776, 256, 0, stream>>>(tgt, qpos, mem, pos, w_in, w_out,
                                      w_gate, b_gate, Aq, Ak, Av, Wb, WOb, Gate);

    gemm_qkv<<<dim3(128, 15), 512, 0, stream>>>(Aq, Ak, Av, Wb, b_in, Qb, Kb, Vb);

    attn<<<dim3(80, 8), 512, 0, stream>>>(Qb, Kb, Vb, PO, PL);

    gemm_og<<<dim3(16, 2, 5), 256, 0, stream>>>(PO, PL, WOb, b_out, OUTf);

    finalize<<<1600, 256, 0, stream>>>(tgt, Gate, OUTf, ln_g, ln_b, out);
}

// Round 11
// 193.602 us; speedup vs baseline: 1.0284x; 1.0284x over previous
//
#include <hip/hip_runtime.h>

// ---------------------------------------------------------------------------
// MoE cross-attention decoder layer on MI355X (gfx950), bf16 MFMA pipeline.
// R20: revert to R17 (best, 192.4us): 256-thread qkv grid (128,2,15), attn
// split-2 (80,8,2), gemm_og 2-split (16,2,5)+guard, all XCD-mod-8 alignments.
// One addition: T14 async-STAGE split at attn's chunk boundary - chunk1's V
// global loads are issued BEFORE compute0 (latency hidden under compute),
// only the ds_write + K1 gld_lds remain between the boundary barriers.
// R19 lessons logged: qkv is pinned at ~55us = bytes/2TB/s regardless of
// staging structure (8 variants); attn split-1 loses more TLP than it saves
// in bytes.
// ---------------------------------------------------------------------------

typedef __bf16 bf16x8 __attribute__((ext_vector_type(8)));
typedef float f32x4 __attribute__((ext_vector_type(4)));
typedef unsigned int u32x4 __attribute__((ext_vector_type(4)));
typedef unsigned int u32x2 __attribute__((ext_vector_type(2)));
typedef unsigned short u16x4 __attribute__((ext_vector_type(4)));
typedef unsigned short us;

__device__ __forceinline__ us f2bf(float f) {
    unsigned u = __builtin_bit_cast(unsigned, f);
    u += 0x7FFFu + ((u >> 16) & 1u);
    return (us)(u >> 16);
}

__device__ __forceinline__ unsigned pack2(float lo, float hi) {
    return (unsigned)f2bf(lo) | ((unsigned)f2bf(hi) << 16);
}

__device__ __forceinline__ float bf2f(us v) {
    unsigned u = ((unsigned)v) << 16;
    return __builtin_bit_cast(float, u);
}

__device__ __forceinline__ bf16x8 ld_bf8(const us* p) {
    return __builtin_bit_cast(bf16x8, *reinterpret_cast<const u32x4*>(p));
}

__device__ __forceinline__ void gld_lds16(const us* g, us* l) {
    __builtin_amdgcn_global_load_lds(
        (const __attribute__((address_space(1))) unsigned int*)g,
        (__attribute__((address_space(3))) unsigned int*)l, 16, 0, 0);
}

// ---------------- fused converts + gate softmax ----------------------------
// Wb is written FRAGMENT-MAJOR: per (e,role) 65536-elem block laid out as
// [g 0..31][col 0..255][8], g = k/8.
__launch_bounds__(256)
__global__ void cvt_all(const float* __restrict__ tgt, const float* __restrict__ qpos,
                        const float* __restrict__ mem, const float* __restrict__ pos,
                        const float* __restrict__ w_in, const float* __restrict__ w_out,
                        const float* __restrict__ w_gate, const float* __restrict__ b_gate,
                        us* __restrict__ Aq, us* __restrict__ Ak, us* __restrict__ Av,
                        us* __restrict__ Wb, us* __restrict__ WOb,
                        float* __restrict__ Gate)
{
    const int bid = blockIdx.x;
    const int tid = threadIdx.x;
    if (bid < 400) {
        const int i = bid * 256 + tid;
        const int lane = tid & 63;
        const int row = i >> 6;                 // = 4*bid + wave
        f32x4 a = reinterpret_cast<const f32x4*>(tgt)[i];
        f32x4 b = reinterpret_cast<const f32x4*>(qpos)[i];
        u16x4 r;
#pragma unroll
        for (int j = 0; j < 4; ++j) r[j] = f2bf(a[j] + b[j]);
        reinterpret_cast<u16x4*>(Aq)[i] = r;
        float g[5];
#pragma unroll
        for (int e = 0; e < 5; ++e) {
            f32x4 wg = *reinterpret_cast<const f32x4*>(w_gate + e * 256 + 4 * lane);
            float p = a[0] * wg[0] + a[1] * wg[1] + a[2] * wg[2] + a[3] * wg[3];
#pragma unroll
            for (int off = 32; off >= 1; off >>= 1) p += __shfl_xor(p, off, 64);
            g[e] = p + b_gate[e];
        }
        float mx = g[0];
#pragma unroll
        for (int e = 1; e < 5; ++e) mx = fmaxf(mx, g[e]);
        float sm = 0.0f;
#pragma unroll
        for (int e = 0; e < 5; ++e) { g[e] = __expf(g[e] - mx); sm += g[e]; }
        const float invs = 1.0f / sm;
        if (lane == 0) {
#pragma unroll
            for (int e = 0; e < 5; ++e) Gate[row * 5 + e] = g[e] * invs;
        }
    } else if (bid < 4496) {
        int i = (bid - 400) * 256 + tid;
        f32x4 m = reinterpret_cast<const f32x4*>(mem)[i];
        f32x4 p = reinterpret_cast<const f32x4*>(pos)[i];
        u16x4 rk, rv;
#pragma unroll
        for (int j = 0; j < 4; ++j) { rk[j] = f2bf(m[j] + p[j]); rv[j] = f2bf(m[j]); }
        reinterpret_cast<u16x4*>(Ak)[i] = rk;
        reinterpret_cast<u16x4*>(Av)[i] = rv;
    } else if (bid < 5456) {
        int i = (bid - 4496) * 256 + tid;       // f32x4 index into w_in
        f32x4 a = reinterpret_cast<const f32x4*>(w_in)[i];
        u16x4 r;
#pragma unroll
        for (int j = 0; j < 4; ++j) r[j] = f2bf(a[j]);
        const int e    = i / 49152;             // 768*64
        const int rem  = i % 49152;
        const int row  = rem >> 6;              // 0..767
        const int kq4  = rem & 63;
        const int role = row >> 8;              // 0=q 1=k 2=v
        const int col  = row & 255;
        const int g    = kq4 >> 1;              // k granule (8 elems)
        const int sub  = kq4 & 1;
        const size_t dst = (size_t)(e * 3 + role) * 65536
                         + ((size_t)(g * 256 + col)) * 8 + sub * 4;
        *reinterpret_cast<u16x4*>(Wb + dst) = r;
    } else {
        int i = (bid - 5456) * 256 + tid;
        f32x4 a = reinterpret_cast<const f32x4*>(w_out)[i];
        u16x4 r;
#pragma unroll
        for (int j = 0; j < 4; ++j) r[j] = f2bf(a[j]);
        reinterpret_cast<u16x4*>(WOb)[i] = r;
    }
}

// ---------------- QKV projection (R14/R17, unchanged) ----------------------
__launch_bounds__(256, 4)
__global__ void gemm_qkv(const us* __restrict__ Aq, const us* __restrict__ Ak,
                         const us* __restrict__ Av, const us* __restrict__ Wb,
                         const float* __restrict__ b_in,
                         us* __restrict__ Qb, us* __restrict__ Kb, us* __restrict__ Vb)
{
    const int rb   = blockIdx.x;       // row block
    const int col0 = blockIdx.y * 128;
    const int zr   = blockIdx.z;       // role-expert
    const us* A; const us* W; const float* bias; us* C;
    float scale; int M;
    if (zr < 5) {
        if (rb >= 13) return;
        A = Aq; W = Wb + (size_t)zr * 196608; bias = b_in + (size_t)zr * 768;
        C = Qb + (size_t)zr * 409600; scale = 0.17677669529663687f; M = 1600;
    } else if (zr < 10) {
        const int e = zr - 5;
        A = Ak; W = Wb + 65536 + (size_t)e * 196608; bias = b_in + (size_t)e * 768 + 256;
        C = Kb + (size_t)e * 4194304; scale = 1.0f; M = 16384;
    } else {
        const int e = zr - 10;
        A = Av; W = Wb + 131072 + (size_t)e * 196608; bias = b_in + (size_t)e * 768 + 512;
        C = Vb + (size_t)e * 4194304; scale = 1.0f; M = 16384;
    }
    const int row0 = rb * 128;

    __shared__ us As[2 * 8192];
    const int tid  = threadIdx.x;
    const int lane = tid & 63;
    const int w    = tid >> 6;
    const int l15  = lane & 15;
    const int quad = lane >> 4;
    const int wm   = (w >> 1) * 64;
    const int wn   = (w & 1) * 64;
    const int srow = lane >> 3;
    const int gofs = ((lane & 7) ^ srow) * 8;

    auto stageA = [&](int buf, int kt) {
#pragma unroll
        for (int cc = 0; cc < 4; ++cc) {
            const int c = w * 4 + cc;
            gld_lds16(A + (size_t)(row0 + c * 8 + srow) * 256 + kt * 64 + gofs,
                      &As[buf * 8192 + c * 512]);
        }
    };

    f32x4 acc[4][4] = {};

    stageA(0, 0);
    __builtin_amdgcn_sched_barrier(0);

#pragma unroll
    for (int kt = 0; kt < 4; ++kt) {
        const int cur = kt & 1;
        u32x4 bf[2][4];
#pragma unroll
        for (int kh = 0; kh < 2; ++kh)
#pragma unroll
            for (int ni = 0; ni < 4; ++ni)
                bf[kh][ni] = *reinterpret_cast<const u32x4*>(
                    W + (((size_t)(kt * 8 + kh * 4 + quad) * 256
                          + (col0 + wn + ni * 16 + l15)) * 8));
        __builtin_amdgcn_sched_barrier(0);
        if (kt < 3) stageA(cur ^ 1, kt + 1);
        __builtin_amdgcn_sched_barrier(0);
        if (kt < 3) asm volatile("s_waitcnt vmcnt(4)" ::: "memory");
        else        asm volatile("s_waitcnt vmcnt(0)" ::: "memory");
        __builtin_amdgcn_s_barrier();
        __builtin_amdgcn_sched_barrier(0);
#pragma unroll
        for (int kh = 0; kh < 2; ++kh) {
            bf16x8 af[4];
#pragma unroll
            for (int mi = 0; mi < 4; ++mi) {
                const int row = wm + mi * 16 + l15;
                const int seg = (kh * 4 + quad) ^ (row & 7);
                af[mi] = ld_bf8(&As[cur * 8192 + row * 64 + seg * 8]);
            }
#pragma unroll
            for (int mi = 0; mi < 4; ++mi)
#pragma unroll
                for (int ni = 0; ni < 4; ++ni)
                    acc[mi][ni] = __builtin_amdgcn_mfma_f32_16x16x32_bf16(
                        __builtin_bit_cast(bf16x8, bf[kh][ni]), af[mi], acc[mi][ni], 0, 0, 0);
        }
        if (kt < 3) {
            asm volatile("s_waitcnt lgkmcnt(0)" ::: "memory");
            __builtin_amdgcn_sched_barrier(0);
            __builtin_amdgcn_s_barrier();
            __builtin_amdgcn_sched_barrier(0);
        }
    }

#pragma unroll
    for (int mi = 0; mi < 4; ++mi) {
        const int row = row0 + wm + mi * 16 + l15;
        if (row < M) {
#pragma unroll
            for (int ni = 0; ni < 4; ++ni) {
                const int colb = col0 + wn + ni * 16 + quad * 4;
                const f32x4 b4 = *reinterpret_cast<const f32x4*>(bias + colb);
                u32x2 pk;
                pk[0] = pack2((acc[mi][ni][0] + b4[0]) * scale,
                              (acc[mi][ni][1] + b4[1]) * scale);
                pk[1] = pack2((acc[mi][ni][2] + b4[2]) * scale,
                              (acc[mi][ni][3] + b4[3]) * scale);
                *reinterpret_cast<u32x2*>(C + (size_t)row * 256 + colb) = pk;
            }
        }
    }
}

// ---------------- out-proj GEMM with fused split-combine (2 splits) --------
// grid (16, 2, 5): x = row block (>=13 idle; pads y-sibling stride to 16 = 0
// mod 8 so both col-blocks' identical PO-row reads hit the same XCD L2).
__launch_bounds__(256)
__global__ void gemm_og(const us* __restrict__ PO, const float* __restrict__ PL,
                        const us* __restrict__ WOb, const float* __restrict__ b_out,
                        float* __restrict__ OUTf)
{
    if (blockIdx.x >= 13) return;
    const int e = blockIdx.z;
    const us* W = WOb + (size_t)e * 65536;
    const float* bias = b_out + (size_t)e * 256;
    float* Cout = OUTf + (size_t)e * 409600;

    const int row0 = blockIdx.x * 128;
    const int col0 = blockIdx.y * 128;
    __shared__ us As[2 * 8192];
    __shared__ us Bs[2 * 8192];
    const int tid  = threadIdx.x;
    const int lane = tid & 63;
    const int w    = tid >> 6;
    const int l15  = lane & 15;
    const int quad = lane >> 4;
    const int wm   = (w >> 1) * 64;
    const int wn   = (w & 1) * 64;
    const int srow = lane >> 3;
    const int gofs = ((lane & 7) ^ srow) * 8;

    u32x4 POr[4][2];   // [chunk][split]
    float Lr[4];

    auto loadA = [&](int kt) {
#pragma unroll
        for (int cc = 0; cc < 4; ++cc) {
            const int c = w * 4 + cc;
            int grow = row0 + c * 8 + srow;
            if (grow > 1599) grow = 1599;
            const int d0 = kt * 64 + gofs;
            const size_t base = (size_t)e * 409600 + (size_t)grow * 256 + d0;
#pragma unroll
            for (int s = 0; s < 2; ++s)
                POr[cc][s] = *reinterpret_cast<const u32x4*>(PO + base + (size_t)s * 2048000);
            const int l = grow >> 4, bb = grow & 15, hh = d0 >> 5;
            float L = 0.0f;
#pragma unroll
            for (int s = 0; s < 2; ++s)
                L += PL[((((size_t)s * 5 + e) * 16 + bb) * 8 + hh) * 128 + l];
            Lr[cc] = L;
        }
    };
    auto writeA = [&](int buf) {
#pragma unroll
        for (int cc = 0; cc < 4; ++cc) {
            const float inv = 1.0f / Lr[cc];
            u32x4 pk;
#pragma unroll
            for (int j = 0; j < 4; ++j) {
                float v0 = 0.0f, v1 = 0.0f;
#pragma unroll
                for (int s = 0; s < 2; ++s) {
                    const unsigned u = POr[cc][s][j];
                    v0 += __builtin_bit_cast(float, u << 16);
                    v1 += __builtin_bit_cast(float, u & 0xffff0000u);
                }
                pk[j] = pack2(v0 * inv, v1 * inv);
            }
            *reinterpret_cast<u32x4*>(&As[buf * 8192 + (w * 4 + cc) * 512 + lane * 8]) = pk;
        }
    };
    auto loadW = [&](int buf, int kt) {
#pragma unroll
        for (int cc = 0; cc < 4; ++cc) {
            const int c = w * 4 + cc;
            const int row = c * 8 + srow;
            gld_lds16(W + (size_t)(col0 + row) * 256 + kt * 64 + gofs,
                      &Bs[buf * 8192 + c * 512]);
        }
    };

    loadA(0);
    loadW(0, 0);
    writeA(0);
    __syncthreads();

    f32x4 acc[4][4] = {};

#pragma unroll
    for (int kt = 0; kt < 4; ++kt) {
        const int cur = kt & 1;
        if (kt < 3) {
            loadA(kt + 1);
            loadW(cur ^ 1, kt + 1);
        }
#pragma unroll
        for (int kh = 0; kh < 2; ++kh) {
            bf16x8 af[4], bf[4];
#pragma unroll
            for (int mi = 0; mi < 4; ++mi) {
                const int row = wm + mi * 16 + l15;
                const int seg = (kh * 4 + quad) ^ (row & 7);
                af[mi] = ld_bf8(&As[cur * 8192 + row * 64 + seg * 8]);
            }
#pragma unroll
            for (int ni = 0; ni < 4; ++ni) {
                const int col = wn + ni * 16 + l15;
                const int seg = (kh * 4 + quad) ^ (col & 7);
                bf[ni] = ld_bf8(&Bs[cur * 8192 + col * 64 + seg * 8]);
            }
#pragma unroll
            for (int mi = 0; mi < 4; ++mi)
#pragma unroll
                for (int ni = 0; ni < 4; ++ni)
                    acc[mi][ni] = __builtin_amdgcn_mfma_f32_16x16x32_bf16(bf[ni], af[mi], acc[mi][ni], 0, 0, 0);
        }
        if (kt < 3) {
            writeA(cur ^ 1);
            __syncthreads();
        }
    }

#pragma unroll
    for (int mi = 0; mi < 4; ++mi) {
        const int row = row0 + wm + mi * 16 + l15;
        if (row < 1600) {
#pragma unroll
            for (int ni = 0; ni < 4; ++ni) {
                const int colb = col0 + wn + ni * 16 + quad * 4;
                const f32x4 b4 = *reinterpret_cast<const f32x4*>(bias + colb);
                f32x4 v;
#pragma unroll
                for (int r = 0; r < 4; ++r) v[r] = acc[mi][ni][r] + b4[r];
                *reinterpret_cast<f32x4*>(Cout + (size_t)row * 256 + colb) = v;
            }
        }
    }
}

// ---------------- split-K attention (R20: T14 V-prefetch at boundary) ------
// grid (80, 8, 2): x = e*16+b, y = head, z = split (XCD-aligned, R16).
__device__ __forceinline__ int vrow(int d) { return d * 264 + 8 * (d >> 3); }

__launch_bounds__(512)
__global__ void attn(const us* __restrict__ Qb, const us* __restrict__ Kb,
                     const us* __restrict__ Vb, us* __restrict__ PO,
                     float* __restrict__ PL)
{
    const int z = blockIdx.x;
    const int h = blockIdx.y;
    const int sp = blockIdx.z;      // split 0/1, each covers 512 keys
    const int e = z >> 4, b = z & 15;
    const int tid  = threadIdx.x;
    const int w    = tid >> 6;
    const int lane = tid & 63;
    const int l15  = lane & 15, quad = lane >> 4;
    __shared__ us Ks[256 * 32];
    __shared__ us Vs[8464];
    __shared__ us Ps[7][2][16 * 40];   // double-buffered per wave

    const int kl  = lane >> 2;
    const int seg = lane & 3;
    const int kv  = tid >> 2;
    const int sg  = tid & 3;

    auto stageK = [&](int key0) {
        const us* kg = Kb + ((size_t)((e * 1024 + key0 + w * 16 + kl) * 16 + b)) * 256
                          + h * 32 + seg * 8;
        gld_lds16(kg, &Ks[w * 512]);
        gld_lds16(kg + (size_t)128 * 16 * 256, &Ks[4096 + w * 512]);
    };
    auto loadV = [&](int key0, u32x4& v0, u32x4& v1) {
        const us* vg = Vb + ((size_t)((e * 1024 + key0 + kv) * 16 + b)) * 256
                          + h * 32 + sg * 8;
        v0 = *reinterpret_cast<const u32x4*>(vg);
        v1 = *reinterpret_cast<const u32x4*>(vg + (size_t)128 * 16 * 256);
    };
    auto writeV = [&](const u32x4& v0, const u32x4& v1) {
#pragma unroll
        for (int j = 0; j < 4; ++j) {
            const int d0 = sg * 8 + 2 * j;
            const int e0 = vrow(d0);
            const int e1 = e0 + 264;
            Vs[e0 + kv]       = (us)(v0[j] & 0xffff);
            Vs[e1 + kv]       = (us)(v0[j] >> 16);
            Vs[e0 + 128 + kv] = (us)(v1[j] & 0xffff);
            Vs[e1 + 128 + kv] = (us)(v1[j] >> 16);
        }
    };

    // Q fragment loaded once
    u32x4 qraw = {0u, 0u, 0u, 0u};
    if (w < 7) {
        const int l = w * 16 + l15;
        if (l < 100)
            qraw = *reinterpret_cast<const u32x4*>(
                Qb + ((size_t)((e * 100 + l) * 16 + b)) * 256 + h * 32 + quad * 8);
    }
    const bf16x8 qf = __builtin_bit_cast(bf16x8, qraw);

    const f32x4 zacc = {};
    f32x4 o0 = {}, o1 = {};
    float lsum = 0.0f;

    auto compute = [&]() {
        auto qk = [&](int c) {
            bf16x8 kf0 = ld_bf8(&Ks[(c * 32 + l15) * 32 + quad * 8]);
            bf16x8 kf1 = ld_bf8(&Ks[(c * 32 + 16 + l15) * 32 + quad * 8]);
            f32x4 s0 = __builtin_amdgcn_mfma_f32_16x16x32_bf16(kf0, qf, zacc, 0, 0, 0);
            f32x4 s1 = __builtin_amdgcn_mfma_f32_16x16x32_bf16(kf1, qf, zacc, 0, 0, 0);
            float p0[4], p1[4];
#pragma unroll
            for (int r = 0; r < 4; ++r) {
                p0[r] = __expf(s0[r]);
                p1[r] = __expf(s1[r]);
                lsum += p0[r] + p1[r];
            }
            u32x2 w0, w1;
            w0[0] = pack2(p0[0], p0[1]);
            w0[1] = pack2(p0[2], p0[3]);
            w1[0] = pack2(p1[0], p1[1]);
            w1[1] = pack2(p1[2], p1[3]);
            us* psb = &Ps[w][c & 1][0];
            *reinterpret_cast<u32x2*>(&psb[l15 * 40 + quad * 4])      = w0;
            *reinterpret_cast<u32x2*>(&psb[l15 * 40 + 16 + quad * 4]) = w1;
        };
        auto pv = [&](int c) {
            bf16x8 pf  = ld_bf8(&Ps[w][c & 1][l15 * 40 + quad * 8]);
            bf16x8 vf0 = ld_bf8(&Vs[vrow(l15) + c * 32 + quad * 8]);
            bf16x8 vf1 = ld_bf8(&Vs[vrow(16 + l15) + c * 32 + quad * 8]);
            o0 = __builtin_amdgcn_mfma_f32_16x16x32_bf16(pf, vf0, o0, 0, 0, 0);
            o1 = __builtin_amdgcn_mfma_f32_16x16x32_bf16(pf, vf1, o1, 0, 0, 0);
        };
        qk(0);
#pragma unroll
        for (int c = 1; c < 8; ++c) {
            qk(c);      // exp VALU of chunk c ...
            pv(c - 1);  // ... overlaps PV MFMA of chunk c-1
        }
        pv(7);
    };

    // ---- chunk 0 staging ----
    const int key0_0 = (sp * 2 + 0) * 256;
    const int key0_1 = (sp * 2 + 1) * 256;
    stageK(key0_0);
    {
        u32x4 v0a, v1a;
        loadV(key0_0, v0a, v1a);
        writeV(v0a, v1a);
    }
    __syncthreads();                 // drains K0 gld_lds + V0 LDS writes

    // T14: issue chunk1's V global loads NOW; they fly during compute0.
    u32x4 v0b, v1b;
    loadV(key0_1, v0b, v1b);

    if (w < 7) compute();            // chunk 0

    __syncthreads();                 // all waves done reading Ks/Vs chunk0
    stageK(key0_1);                  // K1 direct-to-LDS
    writeV(v0b, v1b);                // V1 regs -> LDS (loads long since landed)
    __syncthreads();                 // drains K1 + V1 writes

    if (w < 7) compute();            // chunk 1

    if (w >= 7) return;

    lsum += __shfl_xor(lsum, 16, 64);
    lsum += __shfl_xor(lsum, 32, 64);

#pragma unroll
    for (int r = 0; r < 4; ++r) {
        const int row = w * 16 + quad * 4 + r;
        if (row < 100) {
            const size_t o = (((size_t)((sp * 5 + e) * 100 + row)) * 16 + b) * 256 + h * 32;
            PO[o + l15]      = f2bf(o0[r]);
            PO[o + 16 + l15] = f2bf(o1[r]);
        }
    }
    const int q = w * 16 + l15;
    if (quad == 0 && q < 100)
        PL[((((size_t)sp * 5 + e) * 16 + b) * 8 + h) * 128 + q] = lsum;
}

// ---------------- gate-weighted mix + residual + LayerNorm -----------------
__launch_bounds__(256)
__global__ void finalize(const float* __restrict__ tgt, const float* __restrict__ Gate,
                         const float* __restrict__ OUTf,
                         const float* __restrict__ gamma, const float* __restrict__ beta,
                         float* __restrict__ out)
{
    const int row = blockIdx.x;
    const int d = threadIdx.x;
    __shared__ float red[8];
    const float t = tgt[(size_t)row * 256 + d];

    float mo = 0.0f;
#pragma unroll
    for (int e = 0; e < 5; ++e)
        mo += Gate[row * 5 + e] * OUTf[((size_t)e * 1600 + row) * 256 + d];
    const float x = t + mo;

    float p1 = x, p2 = x * x;
#pragma unroll
    for (int off = 32; off >= 1; off >>= 1) {
        p1 += __shfl_xor(p1, off, 64);
        p2 += __shfl_xor(p2, off, 64);
    }
    if ((d & 63) == 0) { red[d >> 6] = p1; red[4 + (d >> 6)] = p2; }
    __syncthreads();
    const float mean = (red[0] + red[1] + red[2] + red[3]) * (1.0f / 256.0f);
    const float msq  = (red[4] + red[5] + red[6] + red[7]) * (1.0f / 256.0f);
    const float var  = msq - mean * mean;

    out[(size_t)row * 256 + d] = (x - mean) * rsqrtf(var + 1e-5f) * gamma[d] + beta[d];
}

// ---------------------------------------------------------------------------
extern "C" void kernel_launch(void* const* d_in, const int* in_sizes, int n_in,
                              void* d_out, int out_size, void* d_ws, size_t ws_size,
                              hipStream_t stream)
{
    const float* tgt    = (const float*)d_in[0];
    const float* mem    = (const float*)d_in[1];
    const float* qpos   = (const float*)d_in[2];
    const float* pos    = (const float*)d_in[3];
    const float* w_in   = (const float*)d_in[4];
    const float* b_in   = (const float*)d_in[5];
    const float* w_out  = (const float*)d_in[6];
    const float* b_out  = (const float*)d_in[7];
    const float* w_gate = (const float*)d_in[8];
    const float* b_gate = (const float*)d_in[9];
    const float* ln_g   = (const float*)d_in[10];
    const float* ln_b   = (const float*)d_in[11];
    float* out = (float*)d_out;

    char* p = (char*)d_ws;
    auto alloc = [&](size_t n) { char* r = p; p += (n + 255) & ~(size_t)255; return r; };

    us* Aq   = (us*)alloc(409600ull * 2);       // dead after gemm_qkv
    us* Ak   = (us*)alloc(4194304ull * 2);      // dead after gemm_qkv
    us* Av   = (us*)alloc(4194304ull * 2);      // dead after gemm_qkv
    us* Wb   = (us*)alloc(983040ull * 2);
    us* WOb  = (us*)alloc(327680ull * 2);
    us* Qb   = (us*)alloc(5ull * 409600 * 2);
    us* Kb   = (us*)alloc(5ull * 4194304 * 2);
    us* Vb   = (us*)alloc(5ull * 4194304 * 2);
    float* OUTf  = (float*)alloc(5ull * 409600 * 4);
    float* Gate  = (float*)alloc(1600ull * 5 * 4);
    // Attention partials alias the dead cvt region (Aq..Av): 8.2+0.66 < 17.7 MB
    us*    PO = (us*)d_ws;                          // [2][5][100][16][256] bf16
    float* PL = (float*)((char*)d_ws + 8192000);    // [2*5*16*8][128] f32

    cvt_all<<<5776, 256, 0, stream>>>(tgt, qpos, mem, pos, w_in, w_out,
                                      w_gate, b_gate, Aq, Ak, Av, Wb, WOb, Gate);

    gemm_qkv<<<dim3(128, 2, 15), 256, 0, stream>>>(Aq, Ak, Av, Wb, b_in, Qb, Kb, Vb);

    attn<<<dim3(80, 8, 2), 512, 0, stream>>>(Qb, Kb, Vb, PO, PL);

    gemm_og<<<dim3(16, 2, 5), 256, 0, stream>>>(PO, PL, WOb, b_out, OUTf);

    finalize<<<1600, 256, 0, stream>>>(tgt, Gate, OUTf, ln_g, ln_b, out);
}